// Round 1
// baseline (1949.848 us; speedup 1.0000x reference)
//
#include <hip/hip_runtime.h>
#include <hip/hip_bf16.h>
#include <math.h>

// ---------------------------------------------------------------------------
// FeatureNet (DGCNN edge-conv block), MI355X / gfx950, f32 correctness-first.
//
// Pipeline (all on `stream`):
//   zero_stats -> knn_group (g + layer1 moment stats) -> finalize1 (alpha/beta1)
//   -> conv2 (h1 on-the-fly, GEMM W2, y2 + stats2) -> finalize2
//   -> variant A (ws >= 260MB): conv3(store y3 + stats3) -> finalize3 -> out_kernel
//      variant B (ws >= 131MB): conv3(stats only) -> finalize3 -> conv3(fused max->out)
//
// Position ordering p = (b*N + n)*K + kk  (k contiguous -> cheap final max).
// BN folded to per-channel affine alpha*y+beta applied on loads.
// ---------------------------------------------------------------------------

#define B_   16
#define N_   2048
#define KNN  8
#define DIM  128
#define P_   (B_*N_*KNN)   // 262144

// ws layout (bytes)
#define OFF_G     0ull
#define SZ_G      ((size_t)3*P_*4)            // 3,145,728
#define OFF_Y2    (OFF_G + SZ_G)
#define SZ_Y      ((size_t)DIM*P_*4)          // 134,217,728
#define OFF_STATS (OFF_Y2 + SZ_Y)
#define N_STATS   521
#define SZ_STATS  4608ull
#define OFF_AB    (OFF_STATS + SZ_STATS)
#define SZ_AB     4096ull
#define OFF_Y3    (OFF_AB + SZ_AB)
#define NEED_B    (OFF_Y3)
#define NEED_A    (OFF_Y3 + SZ_Y)

// stats (f64) indices
#define I_SG   0    // sum g[c], c=0..2
#define I_SGG  3    // sum g[c]*g[c'] upper-tri: 00,01,02,11,12,22
#define I_S2   9    // per-channel sum of y2
#define I_S2Q  137  // per-channel sum of y2^2
#define I_S3   265
#define I_S3Q  393

__device__ __forceinline__ void atomAddD(double* p, double v) {
    __hip_atomic_fetch_add(p, v, __ATOMIC_RELAXED, __HIP_MEMORY_SCOPE_AGENT);
}

// ---------------------------------------------------------------------------
__global__ void zero_stats_kernel(double* __restrict__ st) {
    for (int i = threadIdx.x; i < N_STATS; i += 256) st[i] = 0.0;
}

// ---------------------------------------------------------------------------
// kNN + grouped offsets + layer-1 moment stats.
// One block = 128 points of one batch; whole batch's x (+|x|^2) staged in LDS.
__global__ __launch_bounds__(128) void knn_group_kernel(
    const float* __restrict__ x, float* __restrict__ g, double* __restrict__ st)
{
    __shared__ float xs0[N_], xs1[N_], xs2[N_], sqs[N_];
    const int b = blockIdx.y;
    const int n = blockIdx.x * 128 + threadIdx.x;
    const float* xb = x + (size_t)b * 3 * N_;
    for (int i = threadIdx.x; i < N_; i += 128) {
        const float a0 = xb[i], a1 = xb[N_ + i], a2 = xb[2*N_ + i];
        xs0[i] = a0; xs1[i] = a1; xs2[i] = a2;
        // match ref: squares rounded individually, left-assoc sum
        sqs[i] = __fadd_rn(__fadd_rn(__fmul_rn(a0,a0), __fmul_rn(a1,a1)), __fmul_rn(a2,a2));
    }
    __syncthreads();
    const float xn0 = xs0[n], xn1 = xs1[n], xn2 = xs2[n], sqn = sqs[n];

    float bd[KNN]; int bi[KNN];
    #pragma unroll
    for (int i = 0; i < KNN; ++i) { bd[i] = INFINITY; bi[i] = 0; }

    #pragma unroll 2
    for (int m = 0; m < N_; ++m) {
        const float inner = __fmaf_rn(xn2, xs2[m], __fmaf_rn(xn1, xs1[m], __fmul_rn(xn0, xs0[m])));
        const float dd = __fadd_rn(__fmaf_rn(-2.f, inner, sqn), sqs[m]);
        if (dd < bd[KNN-1]) {              // strict < : ties keep lower index (matches top_k)
            bd[7] = dd; bi[7] = m;
            #pragma unroll
            for (int j = 7; j > 0; --j) {
                if (bd[j] < bd[j-1]) {
                    const float tf = bd[j]; bd[j] = bd[j-1]; bd[j-1] = tf;
                    const int   ti = bi[j]; bi[j] = bi[j-1]; bi[j-1] = ti;
                }
            }
        }
    }

    float gx[KNN], gy[KNN], gz[KNN];
    float s0=0,s1=0,s2=0,s00=0,s01=0,s02=0,s11=0,s12=0,s22=0;
    #pragma unroll
    for (int kk = 0; kk < KNN; ++kk) {
        const int m = bi[kk];
        const float g0 = xs0[m]-xn0, g1v = xs1[m]-xn1, g2v = xs2[m]-xn2;
        gx[kk]=g0; gy[kk]=g1v; gz[kk]=g2v;
        s0+=g0; s1+=g1v; s2+=g2v;
        s00=fmaf(g0,g0,s00); s01=fmaf(g0,g1v,s01); s02=fmaf(g0,g2v,s02);
        s11=fmaf(g1v,g1v,s11); s12=fmaf(g1v,g2v,s12); s22=fmaf(g2v,g2v,s22);
    }
    const size_t base = ((size_t)b*N_ + n) * KNN;
    float4* gp;
    gp = (float4*)&g[0*P_ + base];
    gp[0] = make_float4(gx[0],gx[1],gx[2],gx[3]); gp[1] = make_float4(gx[4],gx[5],gx[6],gx[7]);
    gp = (float4*)&g[1*P_ + base];
    gp[0] = make_float4(gy[0],gy[1],gy[2],gy[3]); gp[1] = make_float4(gy[4],gy[5],gy[6],gy[7]);
    gp = (float4*)&g[2*P_ + base];
    gp[0] = make_float4(gz[0],gz[1],gz[2],gz[3]); gp[1] = make_float4(gz[4],gz[5],gz[6],gz[7]);

    #pragma unroll
    for (int m = 1; m < 64; m <<= 1) {
        s0+=__shfl_xor(s0,m);  s1+=__shfl_xor(s1,m);  s2+=__shfl_xor(s2,m);
        s00+=__shfl_xor(s00,m); s01+=__shfl_xor(s01,m); s02+=__shfl_xor(s02,m);
        s11+=__shfl_xor(s11,m); s12+=__shfl_xor(s12,m); s22+=__shfl_xor(s22,m);
    }
    if ((threadIdx.x & 63) == 0) {
        atomAddD(&st[I_SG+0], s0);  atomAddD(&st[I_SG+1], s1);  atomAddD(&st[I_SG+2], s2);
        atomAddD(&st[I_SGG+0], s00); atomAddD(&st[I_SGG+1], s01); atomAddD(&st[I_SGG+2], s02);
        atomAddD(&st[I_SGG+3], s11); atomAddD(&st[I_SGG+4], s12); atomAddD(&st[I_SGG+5], s22);
    }
}

// ---------------------------------------------------------------------------
// Layer-1 BN stats from g moments (conv is linear => exact in expectation).
__global__ void finalize1_kernel(
    const double* __restrict__ st, const float* __restrict__ W1,
    const float* __restrict__ b1, const float* __restrict__ g1,
    const float* __restrict__ be1, float* __restrict__ ab)
{
    const int d = threadIdx.x;
    if (d >= DIM) return;
    const double inv = 1.0 / (double)P_;
    const double mu0 = st[0]*inv, mu1 = st[1]*inv, mu2 = st[2]*inv;
    const double c00 = st[3]*inv - mu0*mu0;
    const double c01 = st[4]*inv - mu0*mu1;
    const double c02 = st[5]*inv - mu0*mu2;
    const double c11 = st[6]*inv - mu1*mu1;
    const double c12 = st[7]*inv - mu1*mu2;
    const double c22 = st[8]*inv - mu2*mu2;
    const double w0 = W1[d*3+0], w1 = W1[d*3+1], w2 = W1[d*3+2];
    const double mean = w0*mu0 + w1*mu1 + w2*mu2 + (double)b1[d];
    double var = w0*w0*c00 + w1*w1*c11 + w2*w2*c22
               + 2.0*(w0*w1*c01 + w0*w2*c02 + w1*w2*c12);
    if (var < 0.0) var = 0.0;
    const double r = 1.0 / sqrt(var + 1e-5);
    const double alpha = (double)g1[d] * r;
    ab[d]       = (float)alpha;
    ab[DIM + d] = (float)((double)be1[d] - mean*alpha);
}

__global__ void finalize23_kernel(
    const double* __restrict__ st, int soff,
    const float* __restrict__ gg, const float* __restrict__ bee,
    float* __restrict__ ab, int aoff)
{
    const int d = threadIdx.x;
    if (d >= DIM) return;
    const double inv = 1.0 / (double)P_;
    const double mean = st[soff + d] * inv;
    double var = st[soff + DIM + d] * inv - mean*mean;
    if (var < 0.0) var = 0.0;
    const double r = 1.0 / sqrt(var + 1e-5);
    const double alpha = (double)gg[d] * r;
    ab[aoff + d]       = (float)alpha;
    ab[aoff + DIM + d] = (float)((double)bee[d] - mean*alpha);
}

// ---------------------------------------------------------------------------
// conv2: y2[d][p] = sum_c W2[d][c] * relu(a1[c]*(W1[c].g[p] + b1[c]) + e1[c]) + b2[d]
// Block tile: 128 d x 64 p. Thread (tx 0..15, ty 0..15): 8 d x 4 p.
// W2 staged in 4 chunks of [128][32] (16KB); H tile [128][64] (32KB). LDS 48KB.
__global__ __launch_bounds__(256) void conv2_kernel(
    const float* __restrict__ g,  const float* __restrict__ W1,
    const float* __restrict__ b1, const float* __restrict__ ab,
    const float* __restrict__ W2, const float* __restrict__ b2,
    float* __restrict__ y2, double* __restrict__ stats)
{
    __shared__ __align__(16) float Hs[DIM*64];
    __shared__ __align__(16) float Ws[DIM*32];
    const int tid = threadIdx.x;
    const int p0g = blockIdx.x * 64;

    {   // stage H = h1 computed on the fly (wave w covers c in [32w, 32w+32))
        const int pl = tid & 63;
        const int wv = tid >> 6;
        const float g0v = g[0*P_ + p0g + pl];
        const float g1v = g[1*P_ + p0g + pl];
        const float g2v = g[2*P_ + p0g + pl];
        const float* a1 = ab;
        const float* e1 = ab + DIM;
        #pragma unroll 4
        for (int cc = 0; cc < 32; ++cc) {
            const int c = wv*32 + cc;
            const float s = W1[c*3+0]*g0v + W1[c*3+1]*g1v + W1[c*3+2]*g2v + b1[c];
            Hs[c*64 + pl] = fmaxf(a1[c]*s + e1[c], 0.f);
        }
    }

    const int tx = tid & 15, ty = tid >> 4;
    const int d0 = ty*8, p0 = tx*4;
    float acc[8][4] = {};

    for (int chunk = 0; chunk < 4; ++chunk) {
        __syncthreads();                       // protect Ws (and H on first iter)
        for (int i = tid; i < DIM*32; i += 256)
            Ws[i] = W2[(i>>5)*DIM + chunk*32 + (i&31)];
        __syncthreads();
        #pragma unroll 2
        for (int c4 = 0; c4 < 32; c4 += 4) {
            float4 hv[4];
            #pragma unroll
            for (int t = 0; t < 4; ++t)
                hv[t] = *(const float4*)&Hs[(chunk*32 + c4 + t)*64 + p0];
            float4 wv4[8];
            #pragma unroll
            for (int i = 0; i < 8; ++i)
                wv4[i] = *(const float4*)&Ws[(d0+i)*32 + c4];
            #pragma unroll
            for (int i = 0; i < 8; ++i) {
                const float* wp = (const float*)&wv4[i];
                #pragma unroll
                for (int t = 0; t < 4; ++t) {
                    const float w = wp[t];
                    const float* hp = (const float*)&hv[t];
                    acc[i][0] = fmaf(w, hp[0], acc[i][0]);
                    acc[i][1] = fmaf(w, hp[1], acc[i][1]);
                    acc[i][2] = fmaf(w, hp[2], acc[i][2]);
                    acc[i][3] = fmaf(w, hp[3], acc[i][3]);
                }
            }
        }
    }

    #pragma unroll
    for (int i = 0; i < 8; ++i) {
        const int d = d0 + i;
        const float bb = b2[d];
        const float v0 = acc[i][0]+bb, v1 = acc[i][1]+bb, v2 = acc[i][2]+bb, v3 = acc[i][3]+bb;
        float4 o; o.x=v0; o.y=v1; o.z=v2; o.w=v3;
        *(float4*)&y2[(size_t)d*P_ + p0g + p0] = o;
        float s1 = (v0+v1)+(v2+v3);
        float s2 = (v0*v0+v1*v1)+(v2*v2+v3*v3);
        #pragma unroll
        for (int m = 1; m < 16; m <<= 1) { s1 += __shfl_xor(s1, m); s2 += __shfl_xor(s2, m); }
        if (tx == 0) { atomAddD(&stats[I_S2 + d], s1); atomAddD(&stats[I_S2Q + d], s2); }
    }
}

// ---------------------------------------------------------------------------
// conv3: same GEMM with W3 over h2 = relu(a2*y2 + e2).
// MODE 0: store y3 + stats3 (variant A)
// MODE 1: stats3 only      (variant B pass 1)
// MODE 2: fused BN3+ReLU+max_k -> out (variant B pass 2)
template<int MODE>
__global__ __launch_bounds__(256) void conv3_kernel(
    const float* __restrict__ y2, const float* __restrict__ ab,
    const float* __restrict__ W3, const float* __restrict__ b3,
    float* __restrict__ y3, float* __restrict__ out, double* __restrict__ stats)
{
    __shared__ __align__(16) float Hs[DIM*64];
    __shared__ __align__(16) float Ws[DIM*32];
    const int tid = threadIdx.x;
    const int p0g = blockIdx.x * 64;

    {   // stage H from y2 with folded BN2 + ReLU
        const float* a2 = ab + 2*DIM;
        const float* e2 = ab + 3*DIM;
        #pragma unroll
        for (int it = 0; it < 8; ++it) {
            const int flat = it*256 + tid;
            const int c = flat >> 4;
            const int q = (flat & 15) * 4;
            const float4 v = *(const float4*)&y2[(size_t)c*P_ + p0g + q];
            const float a = a2[c], e = e2[c];
            float4 h;
            h.x = fmaxf(fmaf(a, v.x, e), 0.f);
            h.y = fmaxf(fmaf(a, v.y, e), 0.f);
            h.z = fmaxf(fmaf(a, v.z, e), 0.f);
            h.w = fmaxf(fmaf(a, v.w, e), 0.f);
            *(float4*)&Hs[c*64 + q] = h;
        }
    }

    const int tx = tid & 15, ty = tid >> 4;
    const int d0 = ty*8, p0 = tx*4;
    float acc[8][4] = {};

    for (int chunk = 0; chunk < 4; ++chunk) {
        __syncthreads();
        for (int i = tid; i < DIM*32; i += 256)
            Ws[i] = W3[(i>>5)*DIM + chunk*32 + (i&31)];
        __syncthreads();
        #pragma unroll 2
        for (int c4 = 0; c4 < 32; c4 += 4) {
            float4 hv[4];
            #pragma unroll
            for (int t = 0; t < 4; ++t)
                hv[t] = *(const float4*)&Hs[(chunk*32 + c4 + t)*64 + p0];
            float4 wv4[8];
            #pragma unroll
            for (int i = 0; i < 8; ++i)
                wv4[i] = *(const float4*)&Ws[(d0+i)*32 + c4];
            #pragma unroll
            for (int i = 0; i < 8; ++i) {
                const float* wp = (const float*)&wv4[i];
                #pragma unroll
                for (int t = 0; t < 4; ++t) {
                    const float w = wp[t];
                    const float* hp = (const float*)&hv[t];
                    acc[i][0] = fmaf(w, hp[0], acc[i][0]);
                    acc[i][1] = fmaf(w, hp[1], acc[i][1]);
                    acc[i][2] = fmaf(w, hp[2], acc[i][2]);
                    acc[i][3] = fmaf(w, hp[3], acc[i][3]);
                }
            }
        }
    }

    if constexpr (MODE == 2) {
        const float* a3 = ab + 4*DIM;
        const float* e3 = ab + 5*DIM;
        #pragma unroll
        for (int i = 0; i < 8; ++i) {
            const int d = d0 + i;
            const float bb = b3[d];
            const float a = a3[d], e = e3[d];
            const float m0 = fmaf(a, acc[i][0]+bb, e);
            const float m1 = fmaf(a, acc[i][1]+bb, e);
            const float m2 = fmaf(a, acc[i][2]+bb, e);
            const float m3 = fmaf(a, acc[i][3]+bb, e);
            float mm = fmaxf(fmaxf(m0,m1), fmaxf(m2,m3));
            mm = fmaxf(mm, __shfl_xor(mm, 1));   // combine kk 0..3 with 4..7
            if ((tx & 1) == 0) {
                const int pt = (p0g >> 3) + (tx >> 1);   // = b*N + n
                const int bo = pt >> 11;
                const int nn = pt & (N_-1);
                out[((size_t)bo*DIM + d)*N_ + nn] = fmaxf(mm, 0.f);  // max of relus = relu of max
            }
        }
    } else {
        #pragma unroll
        for (int i = 0; i < 8; ++i) {
            const int d = d0 + i;
            const float bb = b3[d];
            const float v0 = acc[i][0]+bb, v1 = acc[i][1]+bb, v2 = acc[i][2]+bb, v3 = acc[i][3]+bb;
            if constexpr (MODE == 0) {
                float4 o; o.x=v0; o.y=v1; o.z=v2; o.w=v3;
                *(float4*)&y3[(size_t)d*P_ + p0g + p0] = o;
            }
            float s1 = (v0+v1)+(v2+v3);
            float s2 = (v0*v0+v1*v1)+(v2*v2+v3*v3);
            #pragma unroll
            for (int m = 1; m < 16; m <<= 1) { s1 += __shfl_xor(s1, m); s2 += __shfl_xor(s2, m); }
            if (tx == 0) { atomAddD(&stats[I_S3 + d], s1); atomAddD(&stats[I_S3Q + d], s2); }
        }
    }
}

// ---------------------------------------------------------------------------
// Variant A epilogue: out[b,d,n] = max_kk relu(a3*y3 + e3)
__global__ __launch_bounds__(256) void out_kernel(
    const float* __restrict__ y3, const float* __restrict__ ab, float* __restrict__ out)
{
    const size_t idx = (size_t)blockIdx.x*256 + threadIdx.x;   // over B*DIM*N
    const int n = (int)(idx & (N_-1));
    const int d = (int)((idx >> 11) & (DIM-1));
    const int b = (int)(idx >> 18);
    const float a = ab[4*DIM + d], e = ab[5*DIM + d];
    const size_t base = (size_t)d*P_ + ((size_t)b*N_ + n)*KNN;
    const float4 v0 = *(const float4*)&y3[base];
    const float4 v1 = *(const float4*)&y3[base + 4];
    float m = fmaf(a, v0.x, e);
    m = fmaxf(m, fmaf(a, v0.y, e));
    m = fmaxf(m, fmaf(a, v0.z, e));
    m = fmaxf(m, fmaf(a, v0.w, e));
    m = fmaxf(m, fmaf(a, v1.x, e));
    m = fmaxf(m, fmaf(a, v1.y, e));
    m = fmaxf(m, fmaf(a, v1.z, e));
    m = fmaxf(m, fmaf(a, v1.w, e));
    out[idx] = fmaxf(m, 0.f);
}

// ---------------------------------------------------------------------------
extern "C" void kernel_launch(void* const* d_in, const int* in_sizes, int n_in,
                              void* d_out, int out_size, void* d_ws, size_t ws_size,
                              hipStream_t stream) {
    (void)in_sizes; (void)n_in; (void)out_size;
    const float* x   = (const float*)d_in[0];
    const float* W1  = (const float*)d_in[1];
    const float* b1  = (const float*)d_in[2];
    const float* g1  = (const float*)d_in[3];
    const float* be1 = (const float*)d_in[4];
    const float* W2  = (const float*)d_in[5];
    const float* b2  = (const float*)d_in[6];
    const float* g2  = (const float*)d_in[7];
    const float* be2 = (const float*)d_in[8];
    const float* W3  = (const float*)d_in[9];
    const float* b3  = (const float*)d_in[10];
    const float* g3  = (const float*)d_in[11];
    const float* be3 = (const float*)d_in[12];
    // d_in[13] = k (fixed 8)

    float*  out = (float*)d_out;
    char*   ws  = (char*)d_ws;
    float*  g   = (float*)(ws + OFF_G);
    float*  y2  = (float*)(ws + OFF_Y2);
    double* st  = (double*)(ws + OFF_STATS);
    float*  ab  = (float*)(ws + OFF_AB);
    float*  y3  = (float*)(ws + OFF_Y3);

    const bool useA = (ws_size >= NEED_A);

    zero_stats_kernel<<<1, 256, 0, stream>>>(st);
    knn_group_kernel<<<dim3(16, B_), 128, 0, stream>>>(x, g, st);
    finalize1_kernel<<<1, 128, 0, stream>>>(st, W1, b1, g1, be1, ab);
    conv2_kernel<<<P_/64, 256, 0, stream>>>(g, W1, b1, ab, W2, b2, y2, st);
    finalize23_kernel<<<1, 128, 0, stream>>>(st, I_S2, g2, be2, ab, 2*DIM);
    if (useA) {
        conv3_kernel<0><<<P_/64, 256, 0, stream>>>(y2, ab, W3, b3, y3, nullptr, st);
        finalize23_kernel<<<1, 128, 0, stream>>>(st, I_S3, g3, be3, ab, 4*DIM);
        out_kernel<<<(B_*DIM*N_)/256, 256, 0, stream>>>(y3, ab, out);
    } else {
        conv3_kernel<1><<<P_/64, 256, 0, stream>>>(y2, ab, W3, b3, nullptr, nullptr, st);
        finalize23_kernel<<<1, 128, 0, stream>>>(st, I_S3, g3, be3, ab, 4*DIM);
        conv3_kernel<2><<<P_/64, 256, 0, stream>>>(y2, ab, W3, b3, nullptr, out, st);
    }
}

// Round 2
// 563.324 us; speedup vs baseline: 3.4613x; 3.4613x over previous
//
#include <hip/hip_runtime.h>
#include <hip/hip_bf16.h>
#include <math.h>

// ---------------------------------------------------------------------------
// FeatureNet (DGCNN edge-conv block), MI355X / gfx950, f32, round 2.
//
// Round-2 change: conv GEMM restructured to 128d x 128p tiles, 8x8 per thread,
// conflict-free LDS layouts (row stride 128), W pre-transposed to [c][d],
// BN1 folded into W1f, banked f64 stats atomics, float4-packed kNN LDS.
// ---------------------------------------------------------------------------

#define B_   16
#define N_   2048
#define KNN  8
#define DIM  128
#define P_   (B_*N_*KNN)   // 262144

// ws layout (bytes)
#define OFF_G     0ull
#define SZ_G      ((size_t)3*P_*4)
#define OFF_Y2    (OFF_G + SZ_G)
#define SZ_Y      ((size_t)DIM*P_*4)          // 134,217,728
#define OFF_WT2   (OFF_Y2 + SZ_Y)
#define SZ_WT     ((size_t)DIM*DIM*4)         // 65,536
#define OFF_WT3   (OFF_WT2 + SZ_WT)
#define OFF_STATS (OFF_WT3 + SZ_WT)
#define N_STATS   4112
#define SZ_STATS  ((size_t)N_STATS*8)         // 32,896
#define OFF_AB    (OFF_STATS + SZ_STATS)
#define SZ_AB     4096ull                      // 1024 floats
#define OFF_Y3    (OFF_AB + SZ_AB)
#define NEED_A    (OFF_Y3 + SZ_Y)

// stats (f64) indices
#define I_SG   0     // sum g[c], c=0..2
#define I_SGG  3     // sum g[c]*g[c'] upper-tri: 00,01,02,11,12,22
#define I_S2   16    // layer2: 8 banks x (128 sum + 128 sumsq)
#define I_S3   (16 + 8*256)
#define NBANK  8

// ab (float) layout
#define AB_W1F 0     // 128 x float4 folded W1 (a*w0,a*w1,a*w2,a*b1+beta)
#define AB_A2  512
#define AB_E2  640
#define AB_A3  768
#define AB_E3  896

__device__ __forceinline__ void atomAddD(double* p, double v) {
    __hip_atomic_fetch_add(p, v, __ATOMIC_RELAXED, __HIP_MEMORY_SCOPE_AGENT);
}

// ---------------------------------------------------------------------------
__global__ void zero_stats_kernel(double* __restrict__ st) {
    for (int i = threadIdx.x; i < N_STATS; i += 256) st[i] = 0.0;
}

// ---------------------------------------------------------------------------
// W transpose: Wt[c][d] = W[d][c] for W2 and W3 (each 128x128).
__global__ __launch_bounds__(256) void transposeW_kernel(
    const float* __restrict__ W2, const float* __restrict__ W3,
    float* __restrict__ Wt2, float* __restrict__ Wt3)
{
    const int idx = blockIdx.x * 256 + threadIdx.x;   // 0..32767
    const int which = idx >> 14;
    const int r = idx & 16383;
    const int c = r >> 7, d = r & 127;
    const float* src = which ? W3 : W2;
    float* dst = which ? Wt3 : Wt2;
    dst[c*DIM + d] = src[d*DIM + c];   // writes coalesced
}

// ---------------------------------------------------------------------------
// kNN + grouped offsets + layer-1 moment stats. One block = 128 points of one
// batch; whole batch's {x,y,z,|x|^2} packed float4 in LDS (32KB).
// Distance arithmetic bit-identical to the round-1 passing version.
__device__ __forceinline__ void knn_insert(float (&bd)[KNN], int (&bi)[KNN],
                                           float dd, int m) {
    bd[7] = dd; bi[7] = m;
    #pragma unroll
    for (int j = 7; j > 0; --j) {
        if (bd[j] < bd[j-1]) {
            const float tf = bd[j]; bd[j] = bd[j-1]; bd[j-1] = tf;
            const int   ti = bi[j]; bi[j] = bi[j-1]; bi[j-1] = ti;
        }
    }
}

__global__ __launch_bounds__(128) void knn_group_kernel(
    const float* __restrict__ x, float* __restrict__ g, double* __restrict__ st)
{
    __shared__ __align__(16) float4 xs4[N_];
    const int b = blockIdx.y;
    const int n = blockIdx.x * 128 + threadIdx.x;
    const float* xb = x + (size_t)b * 3 * N_;
    for (int i = threadIdx.x; i < N_; i += 128) {
        const float a0 = xb[i], a1 = xb[N_ + i], a2 = xb[2*N_ + i];
        const float sq = __fadd_rn(__fadd_rn(__fmul_rn(a0,a0), __fmul_rn(a1,a1)), __fmul_rn(a2,a2));
        xs4[i] = make_float4(a0, a1, a2, sq);
    }
    __syncthreads();
    const float4 me = xs4[n];
    const float xn0 = me.x, xn1 = me.y, xn2 = me.z, sqn = me.w;

    float bd[KNN]; int bi[KNN];
    #pragma unroll
    for (int i = 0; i < KNN; ++i) { bd[i] = INFINITY; bi[i] = 0; }

    #pragma unroll 1
    for (int m = 0; m < N_; m += 4) {
        const float4 q0 = xs4[m+0];
        const float4 q1 = xs4[m+1];
        const float4 q2 = xs4[m+2];
        const float4 q3 = xs4[m+3];
        #define DIST_(q) __fadd_rn(__fmaf_rn(-2.f, __fmaf_rn(xn2,(q).z,__fmaf_rn(xn1,(q).y,__fmul_rn(xn0,(q).x))), sqn), (q).w)
        float dd;
        dd = DIST_(q0); if (dd < bd[7]) knn_insert(bd, bi, dd, m+0);
        dd = DIST_(q1); if (dd < bd[7]) knn_insert(bd, bi, dd, m+1);
        dd = DIST_(q2); if (dd < bd[7]) knn_insert(bd, bi, dd, m+2);
        dd = DIST_(q3); if (dd < bd[7]) knn_insert(bd, bi, dd, m+3);
        #undef DIST_
    }

    float gx[KNN], gy[KNN], gz[KNN];
    float s0=0,s1=0,s2=0,s00=0,s01=0,s02=0,s11=0,s12=0,s22=0;
    #pragma unroll
    for (int kk = 0; kk < KNN; ++kk) {
        const float4 q = xs4[bi[kk]];
        const float g0 = q.x-xn0, g1v = q.y-xn1, g2v = q.z-xn2;
        gx[kk]=g0; gy[kk]=g1v; gz[kk]=g2v;
        s0+=g0; s1+=g1v; s2+=g2v;
        s00=fmaf(g0,g0,s00); s01=fmaf(g0,g1v,s01); s02=fmaf(g0,g2v,s02);
        s11=fmaf(g1v,g1v,s11); s12=fmaf(g1v,g2v,s12); s22=fmaf(g2v,g2v,s22);
    }
    const size_t base = ((size_t)b*N_ + n) * KNN;
    float4* gp;
    gp = (float4*)&g[0*P_ + base];
    gp[0] = make_float4(gx[0],gx[1],gx[2],gx[3]); gp[1] = make_float4(gx[4],gx[5],gx[6],gx[7]);
    gp = (float4*)&g[1*P_ + base];
    gp[0] = make_float4(gy[0],gy[1],gy[2],gy[3]); gp[1] = make_float4(gy[4],gy[5],gy[6],gy[7]);
    gp = (float4*)&g[2*P_ + base];
    gp[0] = make_float4(gz[0],gz[1],gz[2],gz[3]); gp[1] = make_float4(gz[4],gz[5],gz[6],gz[7]);

    #pragma unroll
    for (int m = 1; m < 64; m <<= 1) {
        s0+=__shfl_xor(s0,m);  s1+=__shfl_xor(s1,m);  s2+=__shfl_xor(s2,m);
        s00+=__shfl_xor(s00,m); s01+=__shfl_xor(s01,m); s02+=__shfl_xor(s02,m);
        s11+=__shfl_xor(s11,m); s12+=__shfl_xor(s12,m); s22+=__shfl_xor(s22,m);
    }
    if ((threadIdx.x & 63) == 0) {
        atomAddD(&st[I_SG+0], s0);  atomAddD(&st[I_SG+1], s1);  atomAddD(&st[I_SG+2], s2);
        atomAddD(&st[I_SGG+0], s00); atomAddD(&st[I_SGG+1], s01); atomAddD(&st[I_SGG+2], s02);
        atomAddD(&st[I_SGG+3], s11); atomAddD(&st[I_SGG+4], s12); atomAddD(&st[I_SGG+5], s22);
    }
}

// ---------------------------------------------------------------------------
// Layer-1 BN stats from g moments; emit folded W1f = {a*w0,a*w1,a*w2,a*b1+beta}.
__global__ void finalize1_kernel(
    const double* __restrict__ st, const float* __restrict__ W1,
    const float* __restrict__ b1, const float* __restrict__ g1,
    const float* __restrict__ be1, float* __restrict__ ab)
{
    const int d = threadIdx.x;
    if (d >= DIM) return;
    const double inv = 1.0 / (double)P_;
    const double mu0 = st[0]*inv, mu1 = st[1]*inv, mu2 = st[2]*inv;
    const double c00 = st[3]*inv - mu0*mu0;
    const double c01 = st[4]*inv - mu0*mu1;
    const double c02 = st[5]*inv - mu0*mu2;
    const double c11 = st[6]*inv - mu1*mu1;
    const double c12 = st[7]*inv - mu1*mu2;
    const double c22 = st[8]*inv - mu2*mu2;
    const double w0 = W1[d*3+0], w1 = W1[d*3+1], w2 = W1[d*3+2];
    const double mean = w0*mu0 + w1*mu1 + w2*mu2 + (double)b1[d];
    double var = w0*w0*c00 + w1*w1*c11 + w2*w2*c22
               + 2.0*(w0*w1*c01 + w0*w2*c02 + w1*w2*c12);
    if (var < 0.0) var = 0.0;
    const double r = 1.0 / sqrt(var + 1e-5);
    const double alpha = (double)g1[d] * r;
    const double beta  = (double)be1[d] - mean*alpha;
    ab[AB_W1F + 4*d + 0] = (float)(alpha * w0);
    ab[AB_W1F + 4*d + 1] = (float)(alpha * w1);
    ab[AB_W1F + 4*d + 2] = (float)(alpha * w2);
    ab[AB_W1F + 4*d + 3] = (float)(alpha * (double)b1[d] + beta);
}

// Layers 2/3: reduce banked sums -> folded affine alpha/beta.
__global__ void finalize23_kernel(
    const double* __restrict__ st, int soff,
    const float* __restrict__ gg, const float* __restrict__ bee,
    float* __restrict__ ab, int aoff)
{
    const int d = threadIdx.x;
    if (d >= DIM) return;
    double s1 = 0.0, s2 = 0.0;
    #pragma unroll
    for (int k = 0; k < NBANK; ++k) {
        s1 += st[soff + k*256 + d];
        s2 += st[soff + k*256 + 128 + d];
    }
    const double inv = 1.0 / (double)P_;
    const double mean = s1 * inv;
    double var = s2 * inv - mean*mean;
    if (var < 0.0) var = 0.0;
    const double r = 1.0 / sqrt(var + 1e-5);
    const double alpha = (double)gg[d] * r;
    ab[aoff + d]       = (float)alpha;
    ab[aoff + 128 + d] = (float)((double)bee[d] - mean*alpha);
}

// ---------------------------------------------------------------------------
// conv GEMM: C[128d][128p block] = Wt^T x H, H built per 32-c chunk in LDS.
// SRC 0: H from g via folded W1f (conv2).  SRC 1: H = relu(a2*y2+e2) (conv3).
// MODE 0: store Y + stats.  MODE 1: stats only.  MODE 2: fused BN3+ReLU+max_k.
template<int SRC, int MODE>
__global__ __launch_bounds__(256) void conv_kernel(
    const float* __restrict__ Hsrc, const float* __restrict__ Wt,
    const float* __restrict__ ab,   const float* __restrict__ bias,
    float* __restrict__ Y, float* __restrict__ out,
    double* __restrict__ stats, int statoff)
{
    __shared__ __align__(16) float Hs[32*128];
    __shared__ __align__(16) float Ws[32*128];
    const int tid = threadIdx.x;
    const int p0g = blockIdx.x * 128;

    const int tx = tid & 15, ty = tid >> 4;
    const int p0 = tx*4, d0 = ty*8;
    const int pq = (tid & 31) * 4;   // staging column (p or d)
    const int cg = tid >> 5;         // staging row group 0..7

    float4 g0q, g1q, g2q;
    if constexpr (SRC == 0) {
        g0q = *(const float4*)&Hsrc[0*P_ + p0g + pq];
        g1q = *(const float4*)&Hsrc[1*P_ + p0g + pq];
        g2q = *(const float4*)&Hsrc[2*P_ + p0g + pq];
    }

    float acc[8][8];
    #pragma unroll
    for (int i = 0; i < 8; ++i)
        #pragma unroll
        for (int j = 0; j < 8; ++j) acc[i][j] = 0.f;

    for (int chunk = 0; chunk < 4; ++chunk) {
        const int c0 = chunk * 32;
        __syncthreads();   // previous chunk's reads done
        if constexpr (SRC == 0) {
            #pragma unroll
            for (int it = 0; it < 4; ++it) {
                const int cr = cg + 8*it;
                const float4 wf = *(const float4*)&ab[AB_W1F + 4*(c0 + cr)];
                float4 h;
                h.x = fmaxf(__fmaf_rn(wf.x, g0q.x, __fmaf_rn(wf.y, g1q.x, __fmaf_rn(wf.z, g2q.x, wf.w))), 0.f);
                h.y = fmaxf(__fmaf_rn(wf.x, g0q.y, __fmaf_rn(wf.y, g1q.y, __fmaf_rn(wf.z, g2q.y, wf.w))), 0.f);
                h.z = fmaxf(__fmaf_rn(wf.x, g0q.z, __fmaf_rn(wf.y, g1q.z, __fmaf_rn(wf.z, g2q.z, wf.w))), 0.f);
                h.w = fmaxf(__fmaf_rn(wf.x, g0q.w, __fmaf_rn(wf.y, g1q.w, __fmaf_rn(wf.z, g2q.w, wf.w))), 0.f);
                *(float4*)&Hs[cr*128 + pq] = h;
            }
        } else {
            #pragma unroll
            for (int it = 0; it < 4; ++it) {
                const int cr = cg + 8*it;
                const int c = c0 + cr;
                const float4 v = *(const float4*)&Hsrc[(size_t)c*P_ + p0g + pq];
                const float a = ab[AB_A2 + c], e = ab[AB_E2 + c];
                float4 h;
                h.x = fmaxf(__fmaf_rn(a, v.x, e), 0.f);
                h.y = fmaxf(__fmaf_rn(a, v.y, e), 0.f);
                h.z = fmaxf(__fmaf_rn(a, v.z, e), 0.f);
                h.w = fmaxf(__fmaf_rn(a, v.w, e), 0.f);
                *(float4*)&Hs[cr*128 + pq] = h;
            }
        }
        #pragma unroll
        for (int it = 0; it < 4; ++it) {
            const int cr = cg + 8*it;
            *(float4*)&Ws[cr*128 + pq] = *(const float4*)&Wt[(size_t)(c0 + cr)*DIM + pq];
        }
        __syncthreads();

        #pragma unroll 4
        for (int cc = 0; cc < 32; ++cc) {
            const float4 h0 = *(const float4*)&Hs[cc*128 + p0];
            const float4 h1 = *(const float4*)&Hs[cc*128 + 64 + p0];
            const float4 w0 = *(const float4*)&Ws[cc*128 + d0];
            const float4 w1 = *(const float4*)&Ws[cc*128 + d0 + 4];
            const float wr[8] = {w0.x,w0.y,w0.z,w0.w,w1.x,w1.y,w1.z,w1.w};
            const float hr[8] = {h0.x,h0.y,h0.z,h0.w,h1.x,h1.y,h1.z,h1.w};
            #pragma unroll
            for (int i = 0; i < 8; ++i)
                #pragma unroll
                for (int j = 0; j < 8; ++j)
                    acc[i][j] = __fmaf_rn(wr[i], hr[j], acc[i][j]);
        }
    }

    if constexpr (MODE == 2) {
        #pragma unroll
        for (int i = 0; i < 8; ++i) {
            const int d = d0 + i;
            const float bb = bias[d];
            const float a = ab[AB_A3 + d], e = ab[AB_E3 + d];
            float mm0, mm1;
            {
                const float m01 = fmaxf(__fmaf_rn(a, acc[i][0]+bb, e), __fmaf_rn(a, acc[i][1]+bb, e));
                const float m23 = fmaxf(__fmaf_rn(a, acc[i][2]+bb, e), __fmaf_rn(a, acc[i][3]+bb, e));
                mm0 = fmaxf(m01, m23);
                const float m45 = fmaxf(__fmaf_rn(a, acc[i][4]+bb, e), __fmaf_rn(a, acc[i][5]+bb, e));
                const float m67 = fmaxf(__fmaf_rn(a, acc[i][6]+bb, e), __fmaf_rn(a, acc[i][7]+bb, e));
                mm1 = fmaxf(m45, m67);
            }
            mm0 = fmaxf(mm0, __shfl_xor(mm0, 1));
            mm1 = fmaxf(mm1, __shfl_xor(mm1, 1));
            if ((tid & 1) == 0) {
                const int ptb = (p0g >> 3) + (tx >> 1);
                {
                    const int pt = ptb;
                    out[((size_t)(pt >> 11)*DIM + d)*N_ + (pt & (N_-1))] = fmaxf(mm0, 0.f);
                }
                {
                    const int pt = ptb + 8;
                    out[((size_t)(pt >> 11)*DIM + d)*N_ + (pt & (N_-1))] = fmaxf(mm1, 0.f);
                }
            }
        }
    } else {
        const int bank = blockIdx.x & (NBANK-1);
        #pragma unroll
        for (int i = 0; i < 8; ++i) {
            const int d = d0 + i;
            const float bb = bias[d];
            float v[8];
            #pragma unroll
            for (int j = 0; j < 8; ++j) v[j] = acc[i][j] + bb;
            if constexpr (MODE == 0) {
                float4 o0; o0.x=v[0]; o0.y=v[1]; o0.z=v[2]; o0.w=v[3];
                float4 o1; o1.x=v[4]; o1.y=v[5]; o1.z=v[6]; o1.w=v[7];
                *(float4*)&Y[(size_t)d*P_ + p0g + p0]      = o0;
                *(float4*)&Y[(size_t)d*P_ + p0g + 64 + p0] = o1;
            }
            float s1 = ((v[0]+v[1])+(v[2]+v[3])) + ((v[4]+v[5])+(v[6]+v[7]));
            float s2 = ((v[0]*v[0]+v[1]*v[1])+(v[2]*v[2]+v[3]*v[3]))
                     + ((v[4]*v[4]+v[5]*v[5])+(v[6]*v[6]+v[7]*v[7]));
            #pragma unroll
            for (int m = 1; m < 16; m <<= 1) { s1 += __shfl_xor(s1, m); s2 += __shfl_xor(s2, m); }
            if ((tid & 15) == 0) {
                atomAddD(&stats[statoff + bank*256 + d], s1);
                atomAddD(&stats[statoff + bank*256 + 128 + d], s2);
            }
        }
    }
}

// ---------------------------------------------------------------------------
// Variant A epilogue: out[b,d,n] = max_kk relu(a3*y3 + e3)
__global__ __launch_bounds__(256) void out_kernel(
    const float* __restrict__ y3, const float* __restrict__ ab, float* __restrict__ out)
{
    const size_t idx = (size_t)blockIdx.x*256 + threadIdx.x;   // over B*DIM*N
    const int n = (int)(idx & (N_-1));
    const int d = (int)((idx >> 11) & (DIM-1));
    const int b = (int)(idx >> 18);
    const float a = ab[AB_A3 + d], e = ab[AB_E3 + d];
    const size_t base = (size_t)d*P_ + ((size_t)b*N_ + n)*KNN;
    const float4 v0 = *(const float4*)&y3[base];
    const float4 v1 = *(const float4*)&y3[base + 4];
    float m = __fmaf_rn(a, v0.x, e);
    m = fmaxf(m, __fmaf_rn(a, v0.y, e));
    m = fmaxf(m, __fmaf_rn(a, v0.z, e));
    m = fmaxf(m, __fmaf_rn(a, v0.w, e));
    m = fmaxf(m, __fmaf_rn(a, v1.x, e));
    m = fmaxf(m, __fmaf_rn(a, v1.y, e));
    m = fmaxf(m, __fmaf_rn(a, v1.z, e));
    m = fmaxf(m, __fmaf_rn(a, v1.w, e));
    out[idx] = fmaxf(m, 0.f);
}

// ---------------------------------------------------------------------------
extern "C" void kernel_launch(void* const* d_in, const int* in_sizes, int n_in,
                              void* d_out, int out_size, void* d_ws, size_t ws_size,
                              hipStream_t stream) {
    (void)in_sizes; (void)n_in; (void)out_size;
    const float* x   = (const float*)d_in[0];
    const float* W1  = (const float*)d_in[1];
    const float* b1  = (const float*)d_in[2];
    const float* g1  = (const float*)d_in[3];
    const float* be1 = (const float*)d_in[4];
    const float* W2  = (const float*)d_in[5];
    const float* b2  = (const float*)d_in[6];
    const float* g2  = (const float*)d_in[7];
    const float* be2 = (const float*)d_in[8];
    const float* W3  = (const float*)d_in[9];
    const float* b3  = (const float*)d_in[10];
    const float* g3  = (const float*)d_in[11];
    const float* be3 = (const float*)d_in[12];

    float*  out = (float*)d_out;
    char*   ws  = (char*)d_ws;
    float*  g   = (float*)(ws + OFF_G);
    float*  y2  = (float*)(ws + OFF_Y2);
    float*  wt2 = (float*)(ws + OFF_WT2);
    float*  wt3 = (float*)(ws + OFF_WT3);
    double* st  = (double*)(ws + OFF_STATS);
    float*  ab  = (float*)(ws + OFF_AB);
    float*  y3  = (float*)(ws + OFF_Y3);

    const bool useA = (ws_size >= NEED_A);

    zero_stats_kernel<<<1, 256, 0, stream>>>(st);
    transposeW_kernel<<<128, 256, 0, stream>>>(W2, W3, wt2, wt3);
    knn_group_kernel<<<dim3(16, B_), 128, 0, stream>>>(x, g, st);
    finalize1_kernel<<<1, 128, 0, stream>>>(st, W1, b1, g1, be1, ab);
    conv_kernel<0,0><<<P_/128, 256, 0, stream>>>(g, wt2, ab, b2, y2, nullptr, st, I_S2);
    finalize23_kernel<<<1, 128, 0, stream>>>(st, I_S2, g2, be2, ab, AB_A2);
    if (useA) {
        conv_kernel<1,0><<<P_/128, 256, 0, stream>>>(y2, wt3, ab, b3, y3, nullptr, st, I_S3);
        finalize23_kernel<<<1, 128, 0, stream>>>(st, I_S3, g3, be3, ab, AB_A3);
        out_kernel<<<(B_*DIM*N_)/256, 256, 0, stream>>>(y3, ab, out);
    } else {
        conv_kernel<1,1><<<P_/128, 256, 0, stream>>>(y2, wt3, ab, b3, nullptr, nullptr, st, I_S3);
        finalize23_kernel<<<1, 128, 0, stream>>>(st, I_S3, g3, be3, ab, AB_A3);
        conv_kernel<1,2><<<P_/128, 256, 0, stream>>>(y2, wt3, ab, b3, nullptr, out, st, I_S3);
    }
}

// Round 3
// 555.891 us; speedup vs baseline: 3.5076x; 1.0134x over previous
//
#include <hip/hip_runtime.h>
#include <hip/hip_bf16.h>
#include <math.h>

// ---------------------------------------------------------------------------
// FeatureNet (DGCNN edge-conv block), MI355X / gfx950, f32, round 3.
//
// Round-3 change: kNN parallelized 4-way per point (4 waves/block, segment
// scan + lex merge). Convs unchanged from round 2.
// ---------------------------------------------------------------------------

#define B_   16
#define N_   2048
#define KNN  8
#define DIM  128
#define P_   (B_*N_*KNN)   // 262144
#define SEG  4             // candidate segments per point

// ws layout (bytes)
#define OFF_G     0ull
#define SZ_G      ((size_t)3*P_*4)
#define OFF_Y2    (OFF_G + SZ_G)
#define SZ_Y      ((size_t)DIM*P_*4)          // 134,217,728
#define OFF_WT2   (OFF_Y2 + SZ_Y)
#define SZ_WT     ((size_t)DIM*DIM*4)         // 65,536
#define OFF_WT3   (OFF_WT2 + SZ_WT)
#define OFF_STATS (OFF_WT3 + SZ_WT)
#define N_STATS   4112
#define SZ_STATS  ((size_t)N_STATS*8)
#define OFF_AB    (OFF_STATS + SZ_STATS)
#define SZ_AB     4096ull
#define OFF_Y3    (OFF_AB + SZ_AB)
#define NEED_A    (OFF_Y3 + SZ_Y)

// stats (f64) indices
#define I_SG   0     // sum g[c], c=0..2
#define I_SGG  3     // sum g[c]*g[c'] upper-tri: 00,01,02,11,12,22
#define I_S2   16    // layer2: 8 banks x (128 sum + 128 sumsq)
#define I_S3   (16 + 8*256)
#define NBANK  8

// ab (float) layout
#define AB_W1F 0     // 128 x float4 folded W1 (a*w0,a*w1,a*w2,a*b1+beta)
#define AB_A2  512
#define AB_E2  640
#define AB_A3  768
#define AB_E3  896

__device__ __forceinline__ void atomAddD(double* p, double v) {
    __hip_atomic_fetch_add(p, v, __ATOMIC_RELAXED, __HIP_MEMORY_SCOPE_AGENT);
}

// ---------------------------------------------------------------------------
__global__ void zero_stats_kernel(double* __restrict__ st) {
    for (int i = threadIdx.x; i < N_STATS; i += 256) st[i] = 0.0;
}

// ---------------------------------------------------------------------------
// W transpose: Wt[c][d] = W[d][c] for W2 and W3 (each 128x128).
__global__ __launch_bounds__(256) void transposeW_kernel(
    const float* __restrict__ W2, const float* __restrict__ W3,
    float* __restrict__ Wt2, float* __restrict__ Wt3)
{
    const int idx = blockIdx.x * 256 + threadIdx.x;   // 0..32767
    const int which = idx >> 14;
    const int r = idx & 16383;
    const int c = r >> 7, d = r & 127;
    const float* src = which ? W3 : W2;
    float* dst = which ? Wt3 : Wt2;
    dst[c*DIM + d] = src[d*DIM + c];
}

// ---------------------------------------------------------------------------
// kNN + grouped offsets + layer-1 moment stats.
// Block = 256 threads = 4 waves. Wave s scans candidate segment s (512 cands)
// for 64 points (one point per lane; candidate read is a wave-uniform LDS
// broadcast). Per-segment sorted top-8 -> LDS -> wave 0 lex-merges, gathers,
// writes g, accumulates stats. Distance arithmetic bit-identical to the
// passing round-1/2 versions; ties resolved by (dist, index) lex order.
__device__ __forceinline__ void knn_insert(float (&bd)[KNN], int (&bi)[KNN],
                                           float dd, int m) {
    bd[7] = dd; bi[7] = m;
    #pragma unroll
    for (int j = 7; j > 0; --j) {
        if (bd[j] < bd[j-1]) {
            const float tf = bd[j]; bd[j] = bd[j-1]; bd[j-1] = tf;
            const int   ti = bi[j]; bi[j] = bi[j-1]; bi[j-1] = ti;
        }
    }
}

__global__ __launch_bounds__(256) void knn_group_kernel(
    const float* __restrict__ x, float* __restrict__ g, double* __restrict__ st)
{
    __shared__ __align__(16) float4 xs4[N_];      // 32 KB {x,y,z,|x|^2}
    __shared__ float cd[8*SEG*64];                // [j][seg][lane] 8 KB
    __shared__ int   ci[8*SEG*64];                // 8 KB
    const int b   = blockIdx.y;
    const int tid = threadIdx.x;
    const int wv  = tid >> 6;        // segment 0..3
    const int ln  = tid & 63;        // local point lane
    const int n   = blockIdx.x * 64 + ln;
    const float* xb = x + (size_t)b * 3 * N_;

    for (int i = tid; i < N_; i += 256) {
        const float a0 = xb[i], a1 = xb[N_ + i], a2 = xb[2*N_ + i];
        const float sq = __fadd_rn(__fadd_rn(__fmul_rn(a0,a0), __fmul_rn(a1,a1)), __fmul_rn(a2,a2));
        xs4[i] = make_float4(a0, a1, a2, sq);
    }
    __syncthreads();
    const float4 me = xs4[n];
    const float xn0 = me.x, xn1 = me.y, xn2 = me.z, sqn = me.w;

    float bd[KNN]; int bi[KNN];
    #pragma unroll
    for (int i = 0; i < KNN; ++i) { bd[i] = INFINITY; bi[i] = 0; }

    const int m0 = wv * (N_/SEG);
    #pragma unroll 1
    for (int i = 0; i < N_/SEG; i += 4) {
        const float4 q0 = xs4[m0 + i + 0];
        const float4 q1 = xs4[m0 + i + 1];
        const float4 q2 = xs4[m0 + i + 2];
        const float4 q3 = xs4[m0 + i + 3];
        #define DIST_(q) __fadd_rn(__fmaf_rn(-2.f, __fmaf_rn(xn2,(q).z,__fmaf_rn(xn1,(q).y,__fmul_rn(xn0,(q).x))), sqn), (q).w)
        float dd;
        dd = DIST_(q0); if (dd < bd[7]) knn_insert(bd, bi, dd, m0+i+0);
        dd = DIST_(q1); if (dd < bd[7]) knn_insert(bd, bi, dd, m0+i+1);
        dd = DIST_(q2); if (dd < bd[7]) knn_insert(bd, bi, dd, m0+i+2);
        dd = DIST_(q3); if (dd < bd[7]) knn_insert(bd, bi, dd, m0+i+3);
        #undef DIST_
    }

    #pragma unroll
    for (int j = 0; j < KNN; ++j) {
        cd[(j*SEG + wv)*64 + ln] = bd[j];
        ci[(j*SEG + wv)*64 + ln] = bi[j];
    }
    __syncthreads();

    if (wv == 0) {
        // 4-way merge of sorted lists, (dist, idx) lexicographic.
        int h0 = 0, h1 = 0, h2 = 0, h3 = 0;
        int fi[KNN];
        #pragma unroll
        for (int j = 0; j < KNN; ++j) {
            const float d0 = cd[(h0*SEG + 0)*64 + ln]; const int i0 = ci[(h0*SEG + 0)*64 + ln];
            const float d1 = cd[(h1*SEG + 1)*64 + ln]; const int i1 = ci[(h1*SEG + 1)*64 + ln];
            const float d2 = cd[(h2*SEG + 2)*64 + ln]; const int i2 = ci[(h2*SEG + 2)*64 + ln];
            const float d3 = cd[(h3*SEG + 3)*64 + ln]; const int i3 = ci[(h3*SEG + 3)*64 + ln];
            const bool a01 = (d0 < d1) || (d0 == d1 && i0 < i1);
            const float da = a01 ? d0 : d1; const int ia = a01 ? i0 : i1; const int sa = a01 ? 0 : 1;
            const bool a23 = (d2 < d3) || (d2 == d3 && i2 < i3);
            const float db = a23 ? d2 : d3; const int ib = a23 ? i2 : i3; const int sb = a23 ? 2 : 3;
            const bool ab = (da < db) || (da == db && ia < ib);
            const int iw = ab ? ia : ib; const int sw = ab ? sa : sb;
            fi[j] = iw;
            h0 += (sw == 0); h1 += (sw == 1); h2 += (sw == 2); h3 += (sw == 3);
        }

        float gx[KNN], gy[KNN], gz[KNN];
        float s0=0,s1=0,s2=0,s00=0,s01=0,s02=0,s11=0,s12=0,s22=0;
        #pragma unroll
        for (int kk = 0; kk < KNN; ++kk) {
            const float4 q = xs4[fi[kk]];
            const float g0 = q.x-xn0, g1v = q.y-xn1, g2v = q.z-xn2;
            gx[kk]=g0; gy[kk]=g1v; gz[kk]=g2v;
            s0+=g0; s1+=g1v; s2+=g2v;
            s00=fmaf(g0,g0,s00); s01=fmaf(g0,g1v,s01); s02=fmaf(g0,g2v,s02);
            s11=fmaf(g1v,g1v,s11); s12=fmaf(g1v,g2v,s12); s22=fmaf(g2v,g2v,s22);
        }
        const size_t base = ((size_t)b*N_ + n) * KNN;
        float4* gp;
        gp = (float4*)&g[0*P_ + base];
        gp[0] = make_float4(gx[0],gx[1],gx[2],gx[3]); gp[1] = make_float4(gx[4],gx[5],gx[6],gx[7]);
        gp = (float4*)&g[1*P_ + base];
        gp[0] = make_float4(gy[0],gy[1],gy[2],gy[3]); gp[1] = make_float4(gy[4],gy[5],gy[6],gy[7]);
        gp = (float4*)&g[2*P_ + base];
        gp[0] = make_float4(gz[0],gz[1],gz[2],gz[3]); gp[1] = make_float4(gz[4],gz[5],gz[6],gz[7]);

        #pragma unroll
        for (int m = 1; m < 64; m <<= 1) {
            s0+=__shfl_xor(s0,m);  s1+=__shfl_xor(s1,m);  s2+=__shfl_xor(s2,m);
            s00+=__shfl_xor(s00,m); s01+=__shfl_xor(s01,m); s02+=__shfl_xor(s02,m);
            s11+=__shfl_xor(s11,m); s12+=__shfl_xor(s12,m); s22+=__shfl_xor(s22,m);
        }
        if (ln == 0) {
            atomAddD(&st[I_SG+0], s0);  atomAddD(&st[I_SG+1], s1);  atomAddD(&st[I_SG+2], s2);
            atomAddD(&st[I_SGG+0], s00); atomAddD(&st[I_SGG+1], s01); atomAddD(&st[I_SGG+2], s02);
            atomAddD(&st[I_SGG+3], s11); atomAddD(&st[I_SGG+4], s12); atomAddD(&st[I_SGG+5], s22);
        }
    }
}

// ---------------------------------------------------------------------------
// Layer-1 BN stats from g moments; emit folded W1f = {a*w0,a*w1,a*w2,a*b1+beta}.
__global__ void finalize1_kernel(
    const double* __restrict__ st, const float* __restrict__ W1,
    const float* __restrict__ b1, const float* __restrict__ g1,
    const float* __restrict__ be1, float* __restrict__ ab)
{
    const int d = threadIdx.x;
    if (d >= DIM) return;
    const double inv = 1.0 / (double)P_;
    const double mu0 = st[0]*inv, mu1 = st[1]*inv, mu2 = st[2]*inv;
    const double c00 = st[3]*inv - mu0*mu0;
    const double c01 = st[4]*inv - mu0*mu1;
    const double c02 = st[5]*inv - mu0*mu2;
    const double c11 = st[6]*inv - mu1*mu1;
    const double c12 = st[7]*inv - mu1*mu2;
    const double c22 = st[8]*inv - mu2*mu2;
    const double w0 = W1[d*3+0], w1 = W1[d*3+1], w2 = W1[d*3+2];
    const double mean = w0*mu0 + w1*mu1 + w2*mu2 + (double)b1[d];
    double var = w0*w0*c00 + w1*w1*c11 + w2*w2*c22
               + 2.0*(w0*w1*c01 + w0*w2*c02 + w1*w2*c12);
    if (var < 0.0) var = 0.0;
    const double r = 1.0 / sqrt(var + 1e-5);
    const double alpha = (double)g1[d] * r;
    const double beta  = (double)be1[d] - mean*alpha;
    ab[AB_W1F + 4*d + 0] = (float)(alpha * w0);
    ab[AB_W1F + 4*d + 1] = (float)(alpha * w1);
    ab[AB_W1F + 4*d + 2] = (float)(alpha * w2);
    ab[AB_W1F + 4*d + 3] = (float)(alpha * (double)b1[d] + beta);
}

// Layers 2/3: reduce banked sums -> folded affine alpha/beta.
__global__ void finalize23_kernel(
    const double* __restrict__ st, int soff,
    const float* __restrict__ gg, const float* __restrict__ bee,
    float* __restrict__ ab, int aoff)
{
    const int d = threadIdx.x;
    if (d >= DIM) return;
    double s1 = 0.0, s2 = 0.0;
    #pragma unroll
    for (int k = 0; k < NBANK; ++k) {
        s1 += st[soff + k*256 + d];
        s2 += st[soff + k*256 + 128 + d];
    }
    const double inv = 1.0 / (double)P_;
    const double mean = s1 * inv;
    double var = s2 * inv - mean*mean;
    if (var < 0.0) var = 0.0;
    const double r = 1.0 / sqrt(var + 1e-5);
    const double alpha = (double)gg[d] * r;
    ab[aoff + d]       = (float)alpha;
    ab[aoff + 128 + d] = (float)((double)bee[d] - mean*alpha);
}

// ---------------------------------------------------------------------------
// conv GEMM: C[128d][128p block] = Wt^T x H, H built per 32-c chunk in LDS.
// SRC 0: H from g via folded W1f (conv2).  SRC 1: H = relu(a2*y2+e2) (conv3).
// MODE 0: store Y + stats.  MODE 1: stats only.  MODE 2: fused BN3+ReLU+max_k.
template<int SRC, int MODE>
__global__ __launch_bounds__(256) void conv_kernel(
    const float* __restrict__ Hsrc, const float* __restrict__ Wt,
    const float* __restrict__ ab,   const float* __restrict__ bias,
    float* __restrict__ Y, float* __restrict__ out,
    double* __restrict__ stats, int statoff)
{
    __shared__ __align__(16) float Hs[32*128];
    __shared__ __align__(16) float Ws[32*128];
    const int tid = threadIdx.x;
    const int p0g = blockIdx.x * 128;

    const int tx = tid & 15, ty = tid >> 4;
    const int p0 = tx*4, d0 = ty*8;
    const int pq = (tid & 31) * 4;   // staging column (p or d)
    const int cg = tid >> 5;         // staging row group 0..7

    float4 g0q, g1q, g2q;
    if constexpr (SRC == 0) {
        g0q = *(const float4*)&Hsrc[0*P_ + p0g + pq];
        g1q = *(const float4*)&Hsrc[1*P_ + p0g + pq];
        g2q = *(const float4*)&Hsrc[2*P_ + p0g + pq];
    }

    float acc[8][8];
    #pragma unroll
    for (int i = 0; i < 8; ++i)
        #pragma unroll
        for (int j = 0; j < 8; ++j) acc[i][j] = 0.f;

    for (int chunk = 0; chunk < 4; ++chunk) {
        const int c0 = chunk * 32;
        __syncthreads();
        if constexpr (SRC == 0) {
            #pragma unroll
            for (int it = 0; it < 4; ++it) {
                const int cr = cg + 8*it;
                const float4 wf = *(const float4*)&ab[AB_W1F + 4*(c0 + cr)];
                float4 h;
                h.x = fmaxf(__fmaf_rn(wf.x, g0q.x, __fmaf_rn(wf.y, g1q.x, __fmaf_rn(wf.z, g2q.x, wf.w))), 0.f);
                h.y = fmaxf(__fmaf_rn(wf.x, g0q.y, __fmaf_rn(wf.y, g1q.y, __fmaf_rn(wf.z, g2q.y, wf.w))), 0.f);
                h.z = fmaxf(__fmaf_rn(wf.x, g0q.z, __fmaf_rn(wf.y, g1q.z, __fmaf_rn(wf.z, g2q.z, wf.w))), 0.f);
                h.w = fmaxf(__fmaf_rn(wf.x, g0q.w, __fmaf_rn(wf.y, g1q.w, __fmaf_rn(wf.z, g2q.w, wf.w))), 0.f);
                *(float4*)&Hs[cr*128 + pq] = h;
            }
        } else {
            #pragma unroll
            for (int it = 0; it < 4; ++it) {
                const int cr = cg + 8*it;
                const int c = c0 + cr;
                const float4 v = *(const float4*)&Hsrc[(size_t)c*P_ + p0g + pq];
                const float a = ab[AB_A2 + c], e = ab[AB_E2 + c];
                float4 h;
                h.x = fmaxf(__fmaf_rn(a, v.x, e), 0.f);
                h.y = fmaxf(__fmaf_rn(a, v.y, e), 0.f);
                h.z = fmaxf(__fmaf_rn(a, v.z, e), 0.f);
                h.w = fmaxf(__fmaf_rn(a, v.w, e), 0.f);
                *(float4*)&Hs[cr*128 + pq] = h;
            }
        }
        #pragma unroll
        for (int it = 0; it < 4; ++it) {
            const int cr = cg + 8*it;
            *(float4*)&Ws[cr*128 + pq] = *(const float4*)&Wt[(size_t)(c0 + cr)*DIM + pq];
        }
        __syncthreads();

        #pragma unroll 4
        for (int cc = 0; cc < 32; ++cc) {
            const float4 h0 = *(const float4*)&Hs[cc*128 + p0];
            const float4 h1 = *(const float4*)&Hs[cc*128 + 64 + p0];
            const float4 w0 = *(const float4*)&Ws[cc*128 + d0];
            const float4 w1 = *(const float4*)&Ws[cc*128 + d0 + 4];
            const float wr[8] = {w0.x,w0.y,w0.z,w0.w,w1.x,w1.y,w1.z,w1.w};
            const float hr[8] = {h0.x,h0.y,h0.z,h0.w,h1.x,h1.y,h1.z,h1.w};
            #pragma unroll
            for (int i = 0; i < 8; ++i)
                #pragma unroll
                for (int j = 0; j < 8; ++j)
                    acc[i][j] = __fmaf_rn(wr[i], hr[j], acc[i][j]);
        }
    }

    if constexpr (MODE == 2) {
        #pragma unroll
        for (int i = 0; i < 8; ++i) {
            const int d = d0 + i;
            const float bb = bias[d];
            const float a = ab[AB_A3 + d], e = ab[AB_E3 + d];
            float mm0, mm1;
            {
                const float m01 = fmaxf(__fmaf_rn(a, acc[i][0]+bb, e), __fmaf_rn(a, acc[i][1]+bb, e));
                const float m23 = fmaxf(__fmaf_rn(a, acc[i][2]+bb, e), __fmaf_rn(a, acc[i][3]+bb, e));
                mm0 = fmaxf(m01, m23);
                const float m45 = fmaxf(__fmaf_rn(a, acc[i][4]+bb, e), __fmaf_rn(a, acc[i][5]+bb, e));
                const float m67 = fmaxf(__fmaf_rn(a, acc[i][6]+bb, e), __fmaf_rn(a, acc[i][7]+bb, e));
                mm1 = fmaxf(m45, m67);
            }
            mm0 = fmaxf(mm0, __shfl_xor(mm0, 1));
            mm1 = fmaxf(mm1, __shfl_xor(mm1, 1));
            if ((tid & 1) == 0) {
                const int ptb = (p0g >> 3) + (tx >> 1);
                {
                    const int pt = ptb;
                    out[((size_t)(pt >> 11)*DIM + d)*N_ + (pt & (N_-1))] = fmaxf(mm0, 0.f);
                }
                {
                    const int pt = ptb + 8;
                    out[((size_t)(pt >> 11)*DIM + d)*N_ + (pt & (N_-1))] = fmaxf(mm1, 0.f);
                }
            }
        }
    } else {
        const int bank = blockIdx.x & (NBANK-1);
        #pragma unroll
        for (int i = 0; i < 8; ++i) {
            const int d = d0 + i;
            const float bb = bias[d];
            float v[8];
            #pragma unroll
            for (int j = 0; j < 8; ++j) v[j] = acc[i][j] + bb;
            if constexpr (MODE == 0) {
                float4 o0; o0.x=v[0]; o0.y=v[1]; o0.z=v[2]; o0.w=v[3];
                float4 o1; o1.x=v[4]; o1.y=v[5]; o1.z=v[6]; o1.w=v[7];
                *(float4*)&Y[(size_t)d*P_ + p0g + p0]      = o0;
                *(float4*)&Y[(size_t)d*P_ + p0g + 64 + p0] = o1;
            }
            float s1 = ((v[0]+v[1])+(v[2]+v[3])) + ((v[4]+v[5])+(v[6]+v[7]));
            float s2 = ((v[0]*v[0]+v[1]*v[1])+(v[2]*v[2]+v[3]*v[3]))
                     + ((v[4]*v[4]+v[5]*v[5])+(v[6]*v[6]+v[7]*v[7]));
            #pragma unroll
            for (int m = 1; m < 16; m <<= 1) { s1 += __shfl_xor(s1, m); s2 += __shfl_xor(s2, m); }
            if ((tid & 15) == 0) {
                atomAddD(&stats[statoff + bank*256 + d], s1);
                atomAddD(&stats[statoff + bank*256 + 128 + d], s2);
            }
        }
    }
}

// ---------------------------------------------------------------------------
// Variant A epilogue: out[b,d,n] = max_kk relu(a3*y3 + e3)
__global__ __launch_bounds__(256) void out_kernel(
    const float* __restrict__ y3, const float* __restrict__ ab, float* __restrict__ out)
{
    const size_t idx = (size_t)blockIdx.x*256 + threadIdx.x;   // over B*DIM*N
    const int n = (int)(idx & (N_-1));
    const int d = (int)((idx >> 11) & (DIM-1));
    const int b = (int)(idx >> 18);
    const float a = ab[AB_A3 + d], e = ab[AB_E3 + d];
    const size_t base = (size_t)d*P_ + ((size_t)b*N_ + n)*KNN;
    const float4 v0 = *(const float4*)&y3[base];
    const float4 v1 = *(const float4*)&y3[base + 4];
    float m = __fmaf_rn(a, v0.x, e);
    m = fmaxf(m, __fmaf_rn(a, v0.y, e));
    m = fmaxf(m, __fmaf_rn(a, v0.z, e));
    m = fmaxf(m, __fmaf_rn(a, v0.w, e));
    m = fmaxf(m, __fmaf_rn(a, v1.x, e));
    m = fmaxf(m, __fmaf_rn(a, v1.y, e));
    m = fmaxf(m, __fmaf_rn(a, v1.z, e));
    m = fmaxf(m, __fmaf_rn(a, v1.w, e));
    out[idx] = fmaxf(m, 0.f);
}

// ---------------------------------------------------------------------------
extern "C" void kernel_launch(void* const* d_in, const int* in_sizes, int n_in,
                              void* d_out, int out_size, void* d_ws, size_t ws_size,
                              hipStream_t stream) {
    (void)in_sizes; (void)n_in; (void)out_size;
    const float* x   = (const float*)d_in[0];
    const float* W1  = (const float*)d_in[1];
    const float* b1  = (const float*)d_in[2];
    const float* g1  = (const float*)d_in[3];
    const float* be1 = (const float*)d_in[4];
    const float* W2  = (const float*)d_in[5];
    const float* b2  = (const float*)d_in[6];
    const float* g2  = (const float*)d_in[7];
    const float* be2 = (const float*)d_in[8];
    const float* W3  = (const float*)d_in[9];
    const float* b3  = (const float*)d_in[10];
    const float* g3  = (const float*)d_in[11];
    const float* be3 = (const float*)d_in[12];

    float*  out = (float*)d_out;
    char*   ws  = (char*)d_ws;
    float*  g   = (float*)(ws + OFF_G);
    float*  y2  = (float*)(ws + OFF_Y2);
    float*  wt2 = (float*)(ws + OFF_WT2);
    float*  wt3 = (float*)(ws + OFF_WT3);
    double* st  = (double*)(ws + OFF_STATS);
    float*  ab  = (float*)(ws + OFF_AB);
    float*  y3  = (float*)(ws + OFF_Y3);

    const bool useA = (ws_size >= NEED_A);

    zero_stats_kernel<<<1, 256, 0, stream>>>(st);
    transposeW_kernel<<<128, 256, 0, stream>>>(W2, W3, wt2, wt3);
    knn_group_kernel<<<dim3(N_/64, B_), 256, 0, stream>>>(x, g, st);
    finalize1_kernel<<<1, 128, 0, stream>>>(st, W1, b1, g1, be1, ab);
    conv_kernel<0,0><<<P_/128, 256, 0, stream>>>(g, wt2, ab, b2, y2, nullptr, st, I_S2);
    finalize23_kernel<<<1, 128, 0, stream>>>(st, I_S2, g2, be2, ab, AB_A2);
    if (useA) {
        conv_kernel<1,0><<<P_/128, 256, 0, stream>>>(y2, wt3, ab, b3, y3, nullptr, st, I_S3);
        finalize23_kernel<<<1, 128, 0, stream>>>(st, I_S3, g3, be3, ab, AB_A3);
        out_kernel<<<(B_*DIM*N_)/256, 256, 0, stream>>>(y3, ab, out);
    } else {
        conv_kernel<1,1><<<P_/128, 256, 0, stream>>>(y2, wt3, ab, b3, nullptr, nullptr, st, I_S3);
        finalize23_kernel<<<1, 128, 0, stream>>>(st, I_S3, g3, be3, ab, AB_A3);
        conv_kernel<1,2><<<P_/128, 256, 0, stream>>>(y2, wt3, ab, b3, nullptr, out, st, I_S3);
    }
}

// Round 4
// 458.322 us; speedup vs baseline: 4.2543x; 1.2129x over previous
//
#include <hip/hip_runtime.h>
#include <hip/hip_bf16.h>
#include <math.h>

// ---------------------------------------------------------------------------
// FeatureNet (DGCNN edge-conv block), MI355X / gfx950, f32, round 4.
//
// Round-4 change: kNN rewritten as wave-per-point bound+compact+select
// (no per-candidate insert-sort). Layer-1 stats via global partials (no hot
// atomics). Convs unchanged from round 2/3.
// ---------------------------------------------------------------------------

#define B_   16
#define N_   2048
#define KNN  8
#define DIM  128
#define P_   (B_*N_*KNN)   // 262144
#define CAP  128           // compacted candidate capacity per point

// ws layout (bytes)
#define OFF_G     0ull
#define SZ_G      ((size_t)3*P_*4)
#define OFF_Y2    (OFF_G + SZ_G)
#define SZ_Y      ((size_t)DIM*P_*4)          // 134,217,728
#define OFF_WT2   (OFF_Y2 + SZ_Y)
#define SZ_WT     ((size_t)DIM*DIM*4)         // 65,536
#define OFF_WT3   (OFF_WT2 + SZ_WT)
#define OFF_STATS (OFF_WT3 + SZ_WT)
#define N_STATS   4112
#define SZ_STATS  ((size_t)N_STATS*8)
#define OFF_AB    (OFF_STATS + SZ_STATS)
#define SZ_AB     4096ull
#define OFF_KPART (OFF_AB + SZ_AB)
#define NKBLK     2048                         // knn blocks (16 points each)
#define SZ_KPART  ((size_t)9*NKBLK*4)          // 73,728
#define OFF_Y3    (OFF_KPART + SZ_KPART)
#define NEED_A    (OFF_Y3 + SZ_Y)

// stats (f64) indices (conv layers only now)
#define I_S2   16    // layer2: 8 banks x (128 sum + 128 sumsq)
#define I_S3   (16 + 8*256)
#define NBANK  8

// ab (float) layout
#define AB_W1F 0     // 128 x float4 folded W1 (a*w0,a*w1,a*w2,a*b1+beta)
#define AB_A2  512
#define AB_E2  640
#define AB_A3  768
#define AB_E3  896

__device__ __forceinline__ void atomAddD(double* p, double v) {
    __hip_atomic_fetch_add(p, v, __ATOMIC_RELAXED, __HIP_MEMORY_SCOPE_AGENT);
}

// ---------------------------------------------------------------------------
__global__ void zero_stats_kernel(double* __restrict__ st) {
    for (int i = threadIdx.x; i < N_STATS; i += 256) st[i] = 0.0;
}

// ---------------------------------------------------------------------------
// W transpose: Wt[c][d] = W[d][c] for W2 and W3 (each 128x128).
__global__ __launch_bounds__(256) void transposeW_kernel(
    const float* __restrict__ W2, const float* __restrict__ W3,
    float* __restrict__ Wt2, float* __restrict__ Wt3)
{
    const int idx = blockIdx.x * 256 + threadIdx.x;   // 0..32767
    const int which = idx >> 14;
    const int r = idx & 16383;
    const int c = r >> 7, d = r & 127;
    const float* src = which ? W3 : W2;
    float* dst = which ? Wt3 : Wt2;
    dst[c*DIM + d] = src[d*DIM + c];
}

// ---------------------------------------------------------------------------
// kNN + grouped offsets + layer-1 moment partials.
// Block = 1024 threads = 16 waves = 16 points. Wave handles one point:
//   Pass A: lane l computes d for candidates l+64i (i<32) in registers; lane
//           min -> B = 8th-smallest of 64 lane minima (upper bound on true
//           8th distance).
//   Pass B: ballot-compact all candidates with d <= B into LDS (superset of
//           the true top-8, ties included).
//   Pass C: 8x wave-wide lex-argmin (d, idx) over the compacted list ==
//           exact jax.lax.top_k selection (stable ties).
// Distance arithmetic bit-identical to the passing round-1/2/3 versions.
__global__ __launch_bounds__(1024) void knn_group_kernel(
    const float* __restrict__ x, float* __restrict__ g, float* __restrict__ kpart)
{
    __shared__ __align__(16) float4 xs4[N_];      // 32 KB {x,y,z,|x|^2}
    __shared__ float listD[16][CAP];              // 8 KB
    __shared__ int   listI[16][CAP];              // 8 KB
    __shared__ float spart[16][12];               // per-wave moment partials
    const int b   = blockIdx.y;
    const int tid = threadIdx.x;
    const int wv  = tid >> 6;        // wave = local point 0..15
    const int ln  = tid & 63;
    const int n   = blockIdx.x * 16 + wv;
    const float* xb = x + (size_t)b * 3 * N_;

    for (int i = tid; i < N_; i += 1024) {
        const float a0 = xb[i], a1 = xb[N_ + i], a2 = xb[2*N_ + i];
        const float sq = __fadd_rn(__fadd_rn(__fmul_rn(a0,a0), __fmul_rn(a1,a1)), __fmul_rn(a2,a2));
        xs4[i] = make_float4(a0, a1, a2, sq);
    }
    __syncthreads();

    const float4 me = xs4[n];
    const float xn0 = me.x, xn1 = me.y, xn2 = me.z, sqn = me.w;

    // ---- Pass A: distances in registers + lane min
    float dreg[32];
    float lmin = INFINITY;
    #pragma unroll
    for (int i = 0; i < 32; ++i) {
        const float4 q = xs4[ln + 64*i];
        dreg[i] = __fadd_rn(__fmaf_rn(-2.f, __fmaf_rn(xn2, q.z, __fmaf_rn(xn1, q.y, __fmul_rn(xn0, q.x))), sqn), q.w);
        lmin = fminf(lmin, dreg[i]);
    }

    // ---- bound B = 8th smallest of the 64 lane minima
    float t = lmin, B = lmin;
    #pragma unroll
    for (int s = 0; s < 8; ++s) {
        float cur = t;
        #pragma unroll
        for (int m = 1; m < 64; m <<= 1) cur = fminf(cur, __shfl_xor(cur, m));
        B = cur;
        t = (t == cur) ? INFINITY : t;
    }

    // ---- Pass B: ballot-compact candidates with d <= B
    unsigned base = 0;
    #pragma unroll
    for (int i = 0; i < 32; ++i) {
        const bool pred = (dreg[i] <= B);
        const unsigned long long mk = __ballot(pred);
        if (pred) {
            const unsigned pos = base + (unsigned)__popcll(mk & ((1ull << ln) - 1ull));
            if (pos < CAP) { listD[wv][pos] = dreg[i]; listI[wv][pos] = ln + 64*i; }
        }
        base += (unsigned)__popcll(mk);
    }
    const int cnt = (base < CAP) ? (int)base : CAP;

    // ---- Pass C: 8x wave lex-argmin over compacted list (exact top_k)
    float cd0 = (ln < cnt)      ? listD[wv][ln]      : INFINITY;
    int   ci0 = (ln < cnt)      ? listI[wv][ln]      : 0x7FFFFFFF;
    float cd1 = (ln + 64 < cnt) ? listD[wv][ln + 64] : INFINITY;
    int   ci1 = (ln + 64 < cnt) ? listI[wv][ln + 64] : 0x7FFFFFFF;
    int myi = 0;   // lane ln<8 ends up with neighbor index of rank ln
    #pragma unroll
    for (int sel = 0; sel < 8; ++sel) {
        const bool sw = (cd1 < cd0) || (cd1 == cd0 && ci1 < ci0);
        float pd = sw ? cd1 : cd0;
        int   pi = sw ? ci1 : ci0;
        #pragma unroll
        for (int m = 1; m < 64; m <<= 1) {
            const float od = __shfl_xor(pd, m);
            const int   oi = __shfl_xor(pi, m);
            if ((od < pd) || (od == pd && oi < pi)) { pd = od; pi = oi; }
        }
        myi = (ln == sel) ? pi : myi;
        if (ci0 == pi) cd0 = INFINITY;
        if (ci1 == pi) cd1 = INFINITY;
    }

    // ---- gather, g-write, stats (lanes 0..7 hold neighbors 0..7)
    if (ln < 8) {
        const float4 q = xs4[myi];
        const float g0  = q.x - xn0;
        const float g1v = q.y - xn1;
        const float g2v = q.z - xn2;
        const size_t basep = ((size_t)b*N_ + n) * KNN;
        g[0*P_ + basep + ln] = g0;
        g[1*P_ + basep + ln] = g1v;
        g[2*P_ + basep + ln] = g2v;
        float s0 = g0, s1 = g1v, s2 = g2v;
        float s00 = g0*g0, s01 = g0*g1v, s02 = g0*g2v;
        float s11 = g1v*g1v, s12 = g1v*g2v, s22 = g2v*g2v;
        #pragma unroll
        for (int m = 1; m < 8; m <<= 1) {
            s0 += __shfl_xor(s0, m);  s1 += __shfl_xor(s1, m);  s2 += __shfl_xor(s2, m);
            s00 += __shfl_xor(s00, m); s01 += __shfl_xor(s01, m); s02 += __shfl_xor(s02, m);
            s11 += __shfl_xor(s11, m); s12 += __shfl_xor(s12, m); s22 += __shfl_xor(s22, m);
        }
        if (ln == 0) {
            spart[wv][0] = s0;  spart[wv][1] = s1;  spart[wv][2] = s2;
            spart[wv][3] = s00; spart[wv][4] = s01; spart[wv][5] = s02;
            spart[wv][6] = s11; spart[wv][7] = s12; spart[wv][8] = s22;
        }
    }
    __syncthreads();
    if (tid < 9) {
        float a = 0.f;
        #pragma unroll
        for (int w = 0; w < 16; ++w) a += spart[w][tid];
        kpart[tid*NKBLK + blockIdx.y*128 + blockIdx.x] = a;
    }
}

// ---------------------------------------------------------------------------
// Layer-1 BN stats from g moment partials; emit folded W1f.
__global__ __launch_bounds__(128) void finalize1_kernel(
    const float* __restrict__ kpart, const float* __restrict__ W1,
    const float* __restrict__ b1, const float* __restrict__ g1,
    const float* __restrict__ be1, float* __restrict__ ab)
{
    __shared__ double red[128];
    __shared__ double S9[9];
    const int tid = threadIdx.x;
    for (int m = 0; m < 9; ++m) {
        double a = 0.0;
        for (int i = tid; i < NKBLK; i += 128) a += (double)kpart[m*NKBLK + i];
        red[tid] = a;
        __syncthreads();
        if (tid == 0) {
            double s = 0.0;
            for (int j = 0; j < 128; ++j) s += red[j];
            S9[m] = s;
        }
        __syncthreads();
    }
    const int d = tid;
    const double inv = 1.0 / (double)P_;
    const double mu0 = S9[0]*inv, mu1 = S9[1]*inv, mu2 = S9[2]*inv;
    const double c00 = S9[3]*inv - mu0*mu0;
    const double c01 = S9[4]*inv - mu0*mu1;
    const double c02 = S9[5]*inv - mu0*mu2;
    const double c11 = S9[6]*inv - mu1*mu1;
    const double c12 = S9[7]*inv - mu1*mu2;
    const double c22 = S9[8]*inv - mu2*mu2;
    const double w0 = W1[d*3+0], w1 = W1[d*3+1], w2 = W1[d*3+2];
    const double mean = w0*mu0 + w1*mu1 + w2*mu2 + (double)b1[d];
    double var = w0*w0*c00 + w1*w1*c11 + w2*w2*c22
               + 2.0*(w0*w1*c01 + w0*w2*c02 + w1*w2*c12);
    if (var < 0.0) var = 0.0;
    const double r = 1.0 / sqrt(var + 1e-5);
    const double alpha = (double)g1[d] * r;
    const double beta  = (double)be1[d] - mean*alpha;
    ab[AB_W1F + 4*d + 0] = (float)(alpha * w0);
    ab[AB_W1F + 4*d + 1] = (float)(alpha * w1);
    ab[AB_W1F + 4*d + 2] = (float)(alpha * w2);
    ab[AB_W1F + 4*d + 3] = (float)(alpha * (double)b1[d] + beta);
}

// Layers 2/3: reduce banked sums -> folded affine alpha/beta.
__global__ void finalize23_kernel(
    const double* __restrict__ st, int soff,
    const float* __restrict__ gg, const float* __restrict__ bee,
    float* __restrict__ ab, int aoff)
{
    const int d = threadIdx.x;
    if (d >= DIM) return;
    double s1 = 0.0, s2 = 0.0;
    #pragma unroll
    for (int k = 0; k < NBANK; ++k) {
        s1 += st[soff + k*256 + d];
        s2 += st[soff + k*256 + 128 + d];
    }
    const double inv = 1.0 / (double)P_;
    const double mean = s1 * inv;
    double var = s2 * inv - mean*mean;
    if (var < 0.0) var = 0.0;
    const double r = 1.0 / sqrt(var + 1e-5);
    const double alpha = (double)gg[d] * r;
    ab[aoff + d]       = (float)alpha;
    ab[aoff + 128 + d] = (float)((double)bee[d] - mean*alpha);
}

// ---------------------------------------------------------------------------
// conv GEMM: C[128d][128p block] = Wt^T x H, H built per 32-c chunk in LDS.
// SRC 0: H from g via folded W1f (conv2).  SRC 1: H = relu(a2*y2+e2) (conv3).
// MODE 0: store Y + stats.  MODE 1: stats only.  MODE 2: fused BN3+ReLU+max_k.
template<int SRC, int MODE>
__global__ __launch_bounds__(256) void conv_kernel(
    const float* __restrict__ Hsrc, const float* __restrict__ Wt,
    const float* __restrict__ ab,   const float* __restrict__ bias,
    float* __restrict__ Y, float* __restrict__ out,
    double* __restrict__ stats, int statoff)
{
    __shared__ __align__(16) float Hs[32*128];
    __shared__ __align__(16) float Ws[32*128];
    const int tid = threadIdx.x;
    const int p0g = blockIdx.x * 128;

    const int tx = tid & 15, ty = tid >> 4;
    const int p0 = tx*4, d0 = ty*8;
    const int pq = (tid & 31) * 4;   // staging column (p or d)
    const int cg = tid >> 5;         // staging row group 0..7

    float4 g0q, g1q, g2q;
    if constexpr (SRC == 0) {
        g0q = *(const float4*)&Hsrc[0*P_ + p0g + pq];
        g1q = *(const float4*)&Hsrc[1*P_ + p0g + pq];
        g2q = *(const float4*)&Hsrc[2*P_ + p0g + pq];
    }

    float acc[8][8];
    #pragma unroll
    for (int i = 0; i < 8; ++i)
        #pragma unroll
        for (int j = 0; j < 8; ++j) acc[i][j] = 0.f;

    for (int chunk = 0; chunk < 4; ++chunk) {
        const int c0 = chunk * 32;
        __syncthreads();
        if constexpr (SRC == 0) {
            #pragma unroll
            for (int it = 0; it < 4; ++it) {
                const int cr = cg + 8*it;
                const float4 wf = *(const float4*)&ab[AB_W1F + 4*(c0 + cr)];
                float4 h;
                h.x = fmaxf(__fmaf_rn(wf.x, g0q.x, __fmaf_rn(wf.y, g1q.x, __fmaf_rn(wf.z, g2q.x, wf.w))), 0.f);
                h.y = fmaxf(__fmaf_rn(wf.x, g0q.y, __fmaf_rn(wf.y, g1q.y, __fmaf_rn(wf.z, g2q.y, wf.w))), 0.f);
                h.z = fmaxf(__fmaf_rn(wf.x, g0q.z, __fmaf_rn(wf.y, g1q.z, __fmaf_rn(wf.z, g2q.z, wf.w))), 0.f);
                h.w = fmaxf(__fmaf_rn(wf.x, g0q.w, __fmaf_rn(wf.y, g1q.w, __fmaf_rn(wf.z, g2q.w, wf.w))), 0.f);
                *(float4*)&Hs[cr*128 + pq] = h;
            }
        } else {
            #pragma unroll
            for (int it = 0; it < 4; ++it) {
                const int cr = cg + 8*it;
                const int c = c0 + cr;
                const float4 v = *(const float4*)&Hsrc[(size_t)c*P_ + p0g + pq];
                const float a = ab[AB_A2 + c], e = ab[AB_E2 + c];
                float4 h;
                h.x = fmaxf(__fmaf_rn(a, v.x, e), 0.f);
                h.y = fmaxf(__fmaf_rn(a, v.y, e), 0.f);
                h.z = fmaxf(__fmaf_rn(a, v.z, e), 0.f);
                h.w = fmaxf(__fmaf_rn(a, v.w, e), 0.f);
                *(float4*)&Hs[cr*128 + pq] = h;
            }
        }
        #pragma unroll
        for (int it = 0; it < 4; ++it) {
            const int cr = cg + 8*it;
            *(float4*)&Ws[cr*128 + pq] = *(const float4*)&Wt[(size_t)(c0 + cr)*DIM + pq];
        }
        __syncthreads();

        #pragma unroll 4
        for (int cc = 0; cc < 32; ++cc) {
            const float4 h0 = *(const float4*)&Hs[cc*128 + p0];
            const float4 h1 = *(const float4*)&Hs[cc*128 + 64 + p0];
            const float4 w0 = *(const float4*)&Ws[cc*128 + d0];
            const float4 w1 = *(const float4*)&Ws[cc*128 + d0 + 4];
            const float wr[8] = {w0.x,w0.y,w0.z,w0.w,w1.x,w1.y,w1.z,w1.w};
            const float hr[8] = {h0.x,h0.y,h0.z,h0.w,h1.x,h1.y,h1.z,h1.w};
            #pragma unroll
            for (int i = 0; i < 8; ++i)
                #pragma unroll
                for (int j = 0; j < 8; ++j)
                    acc[i][j] = __fmaf_rn(wr[i], hr[j], acc[i][j]);
        }
    }

    if constexpr (MODE == 2) {
        #pragma unroll
        for (int i = 0; i < 8; ++i) {
            const int d = d0 + i;
            const float bb = bias[d];
            const float a = ab[AB_A3 + d], e = ab[AB_E3 + d];
            float mm0, mm1;
            {
                const float m01 = fmaxf(__fmaf_rn(a, acc[i][0]+bb, e), __fmaf_rn(a, acc[i][1]+bb, e));
                const float m23 = fmaxf(__fmaf_rn(a, acc[i][2]+bb, e), __fmaf_rn(a, acc[i][3]+bb, e));
                mm0 = fmaxf(m01, m23);
                const float m45 = fmaxf(__fmaf_rn(a, acc[i][4]+bb, e), __fmaf_rn(a, acc[i][5]+bb, e));
                const float m67 = fmaxf(__fmaf_rn(a, acc[i][6]+bb, e), __fmaf_rn(a, acc[i][7]+bb, e));
                mm1 = fmaxf(m45, m67);
            }
            mm0 = fmaxf(mm0, __shfl_xor(mm0, 1));
            mm1 = fmaxf(mm1, __shfl_xor(mm1, 1));
            if ((tid & 1) == 0) {
                const int ptb = (p0g >> 3) + (tx >> 1);
                {
                    const int pt = ptb;
                    out[((size_t)(pt >> 11)*DIM + d)*N_ + (pt & (N_-1))] = fmaxf(mm0, 0.f);
                }
                {
                    const int pt = ptb + 8;
                    out[((size_t)(pt >> 11)*DIM + d)*N_ + (pt & (N_-1))] = fmaxf(mm1, 0.f);
                }
            }
        }
    } else {
        const int bank = blockIdx.x & (NBANK-1);
        #pragma unroll
        for (int i = 0; i < 8; ++i) {
            const int d = d0 + i;
            const float bb = bias[d];
            float v[8];
            #pragma unroll
            for (int j = 0; j < 8; ++j) v[j] = acc[i][j] + bb;
            if constexpr (MODE == 0) {
                float4 o0; o0.x=v[0]; o0.y=v[1]; o0.z=v[2]; o0.w=v[3];
                float4 o1; o1.x=v[4]; o1.y=v[5]; o1.z=v[6]; o1.w=v[7];
                *(float4*)&Y[(size_t)d*P_ + p0g + p0]      = o0;
                *(float4*)&Y[(size_t)d*P_ + p0g + 64 + p0] = o1;
            }
            float s1 = ((v[0]+v[1])+(v[2]+v[3])) + ((v[4]+v[5])+(v[6]+v[7]));
            float s2 = ((v[0]*v[0]+v[1]*v[1])+(v[2]*v[2]+v[3]*v[3]))
                     + ((v[4]*v[4]+v[5]*v[5])+(v[6]*v[6]+v[7]*v[7]));
            #pragma unroll
            for (int m = 1; m < 16; m <<= 1) { s1 += __shfl_xor(s1, m); s2 += __shfl_xor(s2, m); }
            if ((tid & 15) == 0) {
                atomAddD(&stats[statoff + bank*256 + d], s1);
                atomAddD(&stats[statoff + bank*256 + 128 + d], s2);
            }
        }
    }
}

// ---------------------------------------------------------------------------
// Variant A epilogue: out[b,d,n] = max_kk relu(a3*y3 + e3)
__global__ __launch_bounds__(256) void out_kernel(
    const float* __restrict__ y3, const float* __restrict__ ab, float* __restrict__ out)
{
    const size_t idx = (size_t)blockIdx.x*256 + threadIdx.x;   // over B*DIM*N
    const int n = (int)(idx & (N_-1));
    const int d = (int)((idx >> 11) & (DIM-1));
    const int b = (int)(idx >> 18);
    const float a = ab[AB_A3 + d], e = ab[AB_E3 + d];
    const size_t base = (size_t)d*P_ + ((size_t)b*N_ + n)*KNN;
    const float4 v0 = *(const float4*)&y3[base];
    const float4 v1 = *(const float4*)&y3[base + 4];
    float m = __fmaf_rn(a, v0.x, e);
    m = fmaxf(m, __fmaf_rn(a, v0.y, e));
    m = fmaxf(m, __fmaf_rn(a, v0.z, e));
    m = fmaxf(m, __fmaf_rn(a, v0.w, e));
    m = fmaxf(m, __fmaf_rn(a, v1.x, e));
    m = fmaxf(m, __fmaf_rn(a, v1.y, e));
    m = fmaxf(m, __fmaf_rn(a, v1.z, e));
    m = fmaxf(m, __fmaf_rn(a, v1.w, e));
    out[idx] = fmaxf(m, 0.f);
}

// ---------------------------------------------------------------------------
extern "C" void kernel_launch(void* const* d_in, const int* in_sizes, int n_in,
                              void* d_out, int out_size, void* d_ws, size_t ws_size,
                              hipStream_t stream) {
    (void)in_sizes; (void)n_in; (void)out_size;
    const float* x   = (const float*)d_in[0];
    const float* W1  = (const float*)d_in[1];
    const float* b1  = (const float*)d_in[2];
    const float* g1  = (const float*)d_in[3];
    const float* be1 = (const float*)d_in[4];
    const float* W2  = (const float*)d_in[5];
    const float* b2  = (const float*)d_in[6];
    const float* g2  = (const float*)d_in[7];
    const float* be2 = (const float*)d_in[8];
    const float* W3  = (const float*)d_in[9];
    const float* b3  = (const float*)d_in[10];
    const float* g3  = (const float*)d_in[11];
    const float* be3 = (const float*)d_in[12];

    float*  out = (float*)d_out;
    char*   ws  = (char*)d_ws;
    float*  g   = (float*)(ws + OFF_G);
    float*  y2  = (float*)(ws + OFF_Y2);
    float*  wt2 = (float*)(ws + OFF_WT2);
    float*  wt3 = (float*)(ws + OFF_WT3);
    double* st  = (double*)(ws + OFF_STATS);
    float*  ab  = (float*)(ws + OFF_AB);
    float*  kp  = (float*)(ws + OFF_KPART);
    float*  y3  = (float*)(ws + OFF_Y3);

    const bool useA = (ws_size >= NEED_A);

    zero_stats_kernel<<<1, 256, 0, stream>>>(st);
    transposeW_kernel<<<128, 256, 0, stream>>>(W2, W3, wt2, wt3);
    knn_group_kernel<<<dim3(128, B_), 1024, 0, stream>>>(x, g, kp);
    finalize1_kernel<<<1, 128, 0, stream>>>(kp, W1, b1, g1, be1, ab);
    conv_kernel<0,0><<<P_/128, 256, 0, stream>>>(g, wt2, ab, b2, y2, nullptr, st, I_S2);
    finalize23_kernel<<<1, 128, 0, stream>>>(st, I_S2, g2, be2, ab, AB_A2);
    if (useA) {
        conv_kernel<1,0><<<P_/128, 256, 0, stream>>>(y2, wt3, ab, b3, y3, nullptr, st, I_S3);
        finalize23_kernel<<<1, 128, 0, stream>>>(st, I_S3, g3, be3, ab, AB_A3);
        out_kernel<<<(B_*DIM*N_)/256, 256, 0, stream>>>(y3, ab, out);
    } else {
        conv_kernel<1,1><<<P_/128, 256, 0, stream>>>(y2, wt3, ab, b3, nullptr, nullptr, st, I_S3);
        finalize23_kernel<<<1, 128, 0, stream>>>(st, I_S3, g3, be3, ab, AB_A3);
        conv_kernel<1,2><<<P_/128, 256, 0, stream>>>(y2, wt3, ab, b3, nullptr, out, st, I_S3);
    }
}